// Round 3
// baseline (152.758 us; speedup 1.0000x reference)
//
#include <hip/hip_runtime.h>
#include <math.h>

#define N_    64
#define T_    1024
#define E_    512
#define A_    256
#define S_    64
#define O_    80
#define HID_  1024
#define WMAX  19

typedef __attribute__((ext_vector_type(8))) short bh8;
typedef __attribute__((ext_vector_type(4))) float fx4;

__device__ __forceinline__ float sigmoidf_(float x){ return 1.f/(1.f+expf(-x)); }
__device__ __forceinline__ unsigned pk2_(float a, float b){
  unsigned ua = __float_as_uint(a), ub = __float_as_uint(b);
  ua = (ua + 0x7fffu + ((ua>>16)&1u)) >> 16;
  ub = (ub + 0x7fffu + ((ub>>16)&1u)) >> 16;
  return ua | (ub<<16);
}

// =================== generic tiled GEMM body ===================
struct GemmS { float x_s[2][64][68]; float w_s[2][64][68]; };

__device__ void gemm_body(const float* __restrict__ X, int xStride,
                          const float* __restrict__ X2, int Ksplit,
                          const float* __restrict__ W,
                          float* __restrict__ partial,
                          int K, int C, int nMt, int nCt, int KS,
                          int bid, int t, GemmS& sm){
  int mt = bid % nMt; int rest = bid / nMt;
  int ct = rest % nCt; int ks = rest / nCt;
  int m0 = mt << 6; int c0 = ct << 6;
  int M = nMt << 6;
  int nch = (K + 63) >> 6;
  int ch0 = (ks*nch)/KS, ch1 = ((ks+1)*nch)/KS;
  int bi = t >> 4, j = t & 15;
  float4 px[4], pw[4];

  auto ld = [&](int ch){
    int k0 = ch << 6;
    #pragma unroll
    for (int i=0;i<4;i++){
      int lin = i*256+t; int bl = lin>>4, kq = lin&15;
      int k = k0 + (kq<<2);
      float4 v = make_float4(0.f,0.f,0.f,0.f);
      if (k < K){
        if (X2 != nullptr && k >= Ksplit){
          v = *(const float4*)&X2[(size_t)bl*1024 + (k - Ksplit)];
        } else {
          v = *(const float4*)&X[(size_t)(m0+bl)*xStride + k];
        }
      }
      px[i] = v;
    }
    #pragma unroll
    for (int i=0;i<4;i++){
      int lin = i*256+t; int kk = lin>>4, cq = lin&15;
      int k = k0 + kk, c = c0 + (cq<<2);
      float4 v = make_float4(0.f,0.f,0.f,0.f);
      if (k < K && c < C) v = *(const float4*)&W[(size_t)k*C + c];
      pw[i] = v;
    }
  };
  auto st = [&](int buf){
    #pragma unroll
    for (int i=0;i<4;i++){
      int lin = i*256+t; int bl = lin>>4, kq = lin&15;
      *(float4*)&sm.x_s[buf][bl][kq<<2] = px[i];
    }
    #pragma unroll
    for (int i=0;i<4;i++){
      int lin = i*256+t; int kk = lin>>4, cq = lin&15;
      *(float4*)&sm.w_s[buf][kk][cq<<2] = pw[i];
    }
  };

  float4 acc[4];
  #pragma unroll
  for (int m=0;m<4;m++) acc[m] = make_float4(0.f,0.f,0.f,0.f);

  ld(ch0); st(0); __syncthreads();
  int buf = 0;
  for (int ch = ch0; ch < ch1; ++ch){
    if (ch+1 < ch1) ld(ch+1);
    #pragma unroll
    for (int kq=0;kq<16;kq++){
      float4 xv[4], wv[4];
      #pragma unroll
      for (int bb=0;bb<4;bb++) xv[bb] = *(const float4*)&sm.x_s[buf][(bi<<2)+bb][kq<<2];
      #pragma unroll
      for (int kk=0;kk<4;kk++) wv[kk] = *(const float4*)&sm.w_s[buf][(kq<<2)+kk][j<<2];
      #pragma unroll
      for (int bb=0;bb<4;bb++){
        float s0=xv[bb].x, s1=xv[bb].y, s2=xv[bb].z, s3=xv[bb].w;
        acc[bb].x += s0*wv[0].x + s1*wv[1].x + s2*wv[2].x + s3*wv[3].x;
        acc[bb].y += s0*wv[0].y + s1*wv[1].y + s2*wv[2].y + s3*wv[3].y;
        acc[bb].z += s0*wv[0].z + s1*wv[1].z + s2*wv[2].z + s3*wv[3].z;
        acc[bb].w += s0*wv[0].w + s1*wv[1].w + s2*wv[2].w + s3*wv[3].w;
      }
    }
    if (ch+1 < ch1){ st(buf^1); __syncthreads(); }
    buf ^= 1;
  }
  int c = c0 + (j<<2);
  if (c < C){
    #pragma unroll
    for (int bb=0;bb<4;bb++){
      int bl = (bi<<2)+bb;
      *(float4*)&partial[(size_t)(ks*M + m0 + bl)*C + c] = acc[bb];
    }
  }
}

__global__ __launch_bounds__(256) void k_gemmA(const float* __restrict__ X, int xStride,
                                               const float* __restrict__ X2, int Ksplit,
                                               const float* __restrict__ W,
                                               float* __restrict__ partial,
                                               int K, int C, int nMt, int nCt, int KS){
  __shared__ GemmS sm;
  gemm_body(X,xStride,X2,Ksplit,W,partial,K,C,nMt,nCt,KS,blockIdx.x,threadIdx.x,sm);
}

// =================== LSTM gates GEMM body (bf16 MFMA), k-range selectable ===================
struct LstmS { uint4 WlA[2][512]; uint4 XlA[2][512]; float outb[64][68]; };

__device__ void lstm_body(const float* __restrict__ xA, int KxA,
                          const float* __restrict__ xB,
                          const float* __restrict__ Wih,
                          const float* __restrict__ Whh,
                          float* __restrict__ partial, int KS, int Klen,
                          int bid, int t, LstmS& sm){
  int Mblk = bid & 63;
  int ks = bid >> 6;
  int r0 = Mblk << 6;
  int nch = Klen >> 6;
  int ch0 = (ks*nch)/KS, ch1 = ((ks+1)*nch)/KS;
  int wid = t >> 6, lane = t & 63;

  float4 rw[2][2], rx[2][2];
  auto ld = [&](int ch){
    int k0 = ch << 6;
    #pragma unroll
    for (int u=0;u<2;u++){
      int g = t + (u<<8); int row = g>>3; int k = k0 + ((g&7)<<3);
      const float* sw;
      const float* sx;
      if (k < KxA){ sw = &Wih[(size_t)(r0+row)*KxA + k]; sx = &xA[(size_t)row*KxA + k]; }
      else        { sw = &Whh[((size_t)(r0+row)<<10) + (k - KxA)]; sx = &xB[((size_t)row<<10) + (k - KxA)]; }
      rw[u][0] = *(const float4*)sw; rw[u][1] = *(const float4*)(sw+4);
      rx[u][0] = *(const float4*)sx; rx[u][1] = *(const float4*)(sx+4);
    }
  };
  auto cvst = [&](int buf){
    #pragma unroll
    for (int u=0;u<2;u++){
      int g = t + (u<<8); int row = g>>3, gk = g&7;
      int byte = row*128 + ((gk ^ (row&7))<<4);
      uint4 vw, vx;
      vw.x = pk2_(rw[u][0].x, rw[u][0].y); vw.y = pk2_(rw[u][0].z, rw[u][0].w);
      vw.z = pk2_(rw[u][1].x, rw[u][1].y); vw.w = pk2_(rw[u][1].z, rw[u][1].w);
      vx.x = pk2_(rx[u][0].x, rx[u][0].y); vx.y = pk2_(rx[u][0].z, rx[u][0].w);
      vx.z = pk2_(rx[u][1].x, rx[u][1].y); vx.w = pk2_(rx[u][1].z, rx[u][1].w);
      *(uint4*)((char*)&sm.WlA[buf][0] + byte) = vw;
      *(uint4*)((char*)&sm.XlA[buf][0] + byte) = vx;
    }
  };

  fx4 acc[4];
  #pragma unroll
  for (int nt=0;nt<4;nt++) acc[nt] = (fx4){0.f,0.f,0.f,0.f};

  ld(ch0); cvst(0); __syncthreads();
  int buf = 0;
  for (int ch = ch0; ch < ch1; ++ch){
    if (ch+1 < ch1) ld(ch+1);
    int rowA = (wid<<4) + (lane&15);
    #pragma unroll
    for (int s=0;s<2;s++){
      int gA = (s<<2) + (lane>>4);
      bh8 a = *(bh8*)((char*)&sm.WlA[buf][0] + rowA*128 + ((gA ^ (rowA&7))<<4));
      #pragma unroll
      for (int nt=0;nt<4;nt++){
        int rowB = (nt<<4) + (lane&15);
        bh8 bf = *(bh8*)((char*)&sm.XlA[buf][0] + rowB*128 + ((gA ^ (rowB&7))<<4));
        acc[nt] = __builtin_amdgcn_mfma_f32_16x16x32_bf16(a, bf, acc[nt], 0, 0, 0);
      }
    }
    if (ch+1 < ch1){ cvst(buf^1); __syncthreads(); }
    buf ^= 1;
  }
  __syncthreads();
  #pragma unroll
  for (int nt=0;nt<4;nt++){
    #pragma unroll
    for (int q=0;q<4;q++)
      sm.outb[(nt<<4)+(lane&15)][(wid<<4)+((lane>>4)<<2)+q] = acc[nt][q];
  }
  __syncthreads();
  #pragma unroll
  for (int i=0;i<4;i++){
    int idx = i*256+t; int b = idx>>4; int r4 = (idx&15)<<2;
    float4 o = *(const float4*)&sm.outb[b][r4];
    *(float4*)&partial[(size_t)((ks<<6)+b)*4096 + r0 + r4] = o;
  }
}

// I-part standalone kernel (Wih * x only)
__global__ __launch_bounds__(256) void k_lstmI(const float* __restrict__ xA, int KxA,
                                               const float* __restrict__ Wih,
                                               float* __restrict__ partial,
                                               int KS, int Klen){
  __shared__ LstmS sm;
  lstm_body(xA, KxA, nullptr, Wih, nullptr, partial, KS, Klen,
            blockIdx.x, threadIdx.x, sm);
}

// =================== K1: argmax+gather | Wdec GEMM | pre1 GEMM ===================
__global__ __launch_bounds__(256) void k_front3(
    const float* __restrict__ prev, const int* __restrict__ lens,
    const float* __restrict__ enc, const float* __restrict__ indec,
    const float* __restrict__ spkr,
    const float* __restrict__ W1, const float* __restrict__ b1,
    const float* __restrict__ hid, const float* __restrict__ Wdec,
    int* __restrict__ lo_out, int* __restrict__ wl_out,
    float* __restrict__ encw, float* __restrict__ paw,
    float* __restrict__ x0, float* __restrict__ pA,
    float* __restrict__ p1x){
  __shared__ __align__(16) char smem_raw[sizeof(GemmS)];
  int bid = blockIdx.x, t = threadIdx.x;

  if (bid < 64){
    int n = bid;
    float* sv = (float*)smem_raw;
    int*   si = (int*)(smem_raw + 1024);
    int*   meta = (int*)(smem_raw + 2048);
    const float* p = prev + n*T_;
    float bv = -1e30f; int bi2 = 0x7fffffff;
    #pragma unroll
    for (int i=0;i<4;i++){
      int idx = t + (i<<8);
      float v = p[idx];
      if (v > bv || (v == bv && idx < bi2)){ bv = v; bi2 = idx; }
    }
    sv[t]=bv; si[t]=bi2; __syncthreads();
    for (int s=128; s>0; s>>=1){
      if (t < s){
        float v2 = sv[t+s]; int i2 = si[t+s];
        if (v2 > sv[t] || (v2 == sv[t] && i2 < si[t])){ sv[t]=v2; si[t]=i2; }
      }
      __syncthreads();
    }
    if (t==0){
      int len = lens[n]; len = len < 1 ? 1 : (len > T_ ? T_ : len);
      int idx = si[0];
      int lo = idx - 9; lo = lo < 0 ? 0 : lo; if (lo > len-1) lo = len-1;
      int hi = idx + 9; hi = hi < 0 ? 0 : hi; if (hi > len-1) hi = len-1;
      meta[0] = lo; meta[1] = hi - lo + 1;
      lo_out[n] = lo; wl_out[n] = hi - lo + 1;
    }
    __syncthreads();
    int lo = meta[0], wl = meta[1];
    #pragma unroll
    for (int i=0;i<10;i++){
      int lin = i*256 + t;
      int r = lin >> 7, e4 = (lin & 127) << 2;
      if (r < WMAX){
        float4 v = make_float4(0.f,0.f,0.f,0.f);
        if (r < wl) v = *(const float4*)&enc[(size_t)((n<<10)+lo+r)*E_ + e4];
        *(float4*)&encw[(size_t)(n*WMAX + r)*E_ + e4] = v;
      }
    }
    if (t < 49){
      int tt = lo - 15 + t;
      paw[n*49 + t] = (tt >= 0 && tt < T_) ? prev[(n<<10)+tt] : 0.f;
    }
    if (t < 16)
      *(float4*)&x0[n*832 + 768 + (t<<2)] = *(const float4*)&spkr[(n<<6) + (t<<2)];

  } else if (bid < 96){
    gemm_body(hid, 1024, hid + 64*1024, 1024, Wdec,
              pA, 2048, 256, 1, 4, 8, bid - 64, t, *(GemmS*)smem_raw);

  } else {
    // pre1 GEMM (8 blocks), X (64x144) in LDS, full output + bias + relu
    int d = bid - 96;
    float* xs = (float*)smem_raw;
    #pragma unroll
    for (int i=0;i<9;i++){
      int q = i*256 + t;
      if (q < 2304){
        int b = q/36; int k4 = (q - b*36) << 2;
        float4 v;
        if (k4 < O_) v = *(const float4*)&indec[b*O_ + k4];
        else         v = *(const float4*)&spkr[(b<<6) + (k4-O_)];
        *(float4*)&xs[b*144 + k4] = v;
      }
    }
    __syncthreads();
    int bi = t >> 4, j = t & 15;
    int c0 = (d<<6) + (j<<2);
    float4 acc[4];
    #pragma unroll
    for (int rr=0;rr<4;rr++) acc[rr] = make_float4(0.f,0.f,0.f,0.f);
    #pragma unroll 4
    for (int k=0;k<144;k++){
      float4 wv = *(const float4*)&W1[(size_t)k*512 + c0];
      #pragma unroll
      for (int rr=0;rr<4;rr++){
        float xv = xs[((bi<<2)+rr)*144 + k];
        acc[rr].x += xv*wv.x; acc[rr].y += xv*wv.y; acc[rr].z += xv*wv.z; acc[rr].w += xv*wv.w;
      }
    }
    float4 bv = *(const float4*)&b1[c0];
    #pragma unroll
    for (int rr=0;rr<4;rr++){
      float4 o;
      o.x = fmaxf(acc[rr].x + bv.x, 0.f);
      o.y = fmaxf(acc[rr].y + bv.y, 0.f);
      o.z = fmaxf(acc[rr].z + bv.z, 0.f);
      o.w = fmaxf(acc[rr].w + bv.w, 0.f);
      *(float4*)&p1x[(size_t)((bi<<2)+rr)*512 + c0] = o;
    }
  }
}

// =================== K2: enc GEMM | pre2 GEMM | LSTM0-Whh | LSTM1-Whh ===================
__global__ __launch_bounds__(256) void k_mega(const float* __restrict__ encw,
    const float* __restrict__ Wenc, float* __restrict__ pE,
    const float* __restrict__ p1x, const float* __restrict__ W2,
    float* __restrict__ pP2,
    const float* __restrict__ hid,
    const float* __restrict__ Whh0, const float* __restrict__ Whh1,
    float* __restrict__ pL0, float* __restrict__ pL1){
  __shared__ __align__(16) char smem_raw[sizeof(GemmS)];
  int bid = blockIdx.x, t = threadIdx.x;
  if (bid < 304){
    gemm_body(encw, 512, nullptr, 0, Wenc, pE, 512, 256, 19, 4, 4, bid, t, *(GemmS*)smem_raw);
  } else if (bid < 320){
    gemm_body(p1x, 512, nullptr, 0, W2, pP2, 512, 256, 1, 4, 4, bid-304, t, *(GemmS*)smem_raw);
  } else if (bid < 576){
    lstm_body(nullptr, 0, hid, nullptr, Whh0, pL0, 4, 1024, bid-320, t, *(LstmS*)smem_raw);
  } else {
    lstm_body(nullptr, 0, hid + 64*1024, nullptr, Whh1, pL1, 4, 1024, bid-576, t, *(LstmS*)smem_raw);
  }
}

// =================== K3: attention epilogue+softmax+ctx | pre2 combine ===================
__global__ __launch_bounds__(256) void k_att2(const float* __restrict__ pE,
    const float* __restrict__ pA, const float* __restrict__ benc,
    const float* __restrict__ convw, const float* __restrict__ Wproj,
    const float* __restrict__ spkr, const float* __restrict__ Wspkr,
    const float* __restrict__ paw, const int* __restrict__ wl_w,
    const float* __restrict__ encw,
    const float* __restrict__ pP2, const float* __restrict__ b2,
    float* __restrict__ x0, float* __restrict__ ctxb){
  __shared__ float cw_s[256*31];
  __shared__ float cv_s[WMAX*256];
  __shared__ float attb_s[256];
  __shared__ float pa_s[49];
  __shared__ float wlog_s[WMAX];
  __shared__ float w_s[WMAX];
  int t = threadIdx.x;

  if (blockIdx.x >= 64){
    int idx = (blockIdx.x - 64)*256 + t;
    int b = idx >> 6; int c4 = (idx & 63) << 2;
    float4 v = *(const float4*)&b2[c4];
    #pragma unroll
    for (int p=0;p<4;p++){
      float4 u = *(const float4*)&pP2[(size_t)((p<<6)+b)*A_ + c4];
      v.x+=u.x; v.y+=u.y; v.z+=u.z; v.w+=u.w;
    }
    v.x=fmaxf(v.x,0.f); v.y=fmaxf(v.y,0.f); v.z=fmaxf(v.z,0.f); v.w=fmaxf(v.w,0.f);
    *(float4*)&x0[b*832 + c4] = v;
    return;
  }

  int n = blockIdx.x;
  int wl = wl_w[n];
  for (int lin = t; lin < 256*31; lin += 256) cw_s[lin] = convw[lin];
  if (t < 49) pa_s[t] = paw[n*49 + t];
  {
    float v = 0.f;
    #pragma unroll
    for (int p=0;p<8;p++) v += pA[(size_t)((p<<6)+n)*A_ + t];
    float sd = 0.f;
    #pragma unroll 16
    for (int s=0;s<S_;s++) sd += spkr[(n<<6)+s]*Wspkr[(s<<8)+t];
    attb_s[t] = v + sd/(1.f+fabsf(sd));
  }
  __syncthreads();
  for (int r=0; r<wl; ++r){
    float cv = 0.f;
    #pragma unroll
    for (int k=0;k<31;k++) cv += cw_s[t*31+k]*pa_s[r+k];
    cv_s[(r<<8)+t] = cv;
  }
  __syncthreads();
  int wid = t>>6, lane = t&63, a0 = lane<<2;
  float4 be4 = *(const float4*)&benc[a0];
  float4 wp4 = *(const float4*)&Wproj[a0];
  float4 ab4 = *(const float4*)&attb_s[a0];
  for (int r = wid; r < wl; r += 4){
    float4 sv = make_float4(0.f,0.f,0.f,0.f);
    #pragma unroll
    for (int ks=0;ks<4;ks++){
      const float4 u = *(const float4*)&pE[(size_t)(ks*1216 + n*WMAX + r)*A_ + a0];
      sv.x+=u.x; sv.y+=u.y; sv.z+=u.z; sv.w+=u.w;
    }
    sv.x += be4.x; sv.y += be4.y; sv.z += be4.z; sv.w += be4.w;
    const float4 cv4 = *(const float4*)&cv_s[(r<<8)+a0];
    float e0 = sv.x/(1.f+fabsf(sv.x)) + ab4.x + cv4.x;
    float e1 = sv.y/(1.f+fabsf(sv.y)) + ab4.y + cv4.y;
    float e2 = sv.z/(1.f+fabsf(sv.z)) + ab4.z + cv4.z;
    float e3 = sv.w/(1.f+fabsf(sv.w)) + ab4.w + cv4.w;
    float vv = tanhf(e0)*wp4.x + tanhf(e1)*wp4.y + tanhf(e2)*wp4.z + tanhf(e3)*wp4.w;
    #pragma unroll
    for (int off=32; off; off >>= 1) vv += __shfl_xor(vv, off, 64);
    if (lane == 0) wlog_s[r] = vv;
  }
  __syncthreads();
  if (t < 32){
    float l = (t < wl) ? wlog_s[t] : -1e30f;
    float mx = l;
    #pragma unroll
    for (int off=16; off; off >>= 1) mx = fmaxf(mx, __shfl_xor(mx, off, 32));
    float ex = (t < wl) ? expf(l - mx) : 0.f;
    float sm = ex;
    #pragma unroll
    for (int off=16; off; off >>= 1) sm += __shfl_xor(sm, off, 32);
    if (t < wl) w_s[t] = ex / sm;
  }
  __syncthreads();
  if (t < 128){
    float4 a = make_float4(0.f,0.f,0.f,0.f);
    for (int r=0; r<wl; ++r){
      float wv = w_s[r];
      const float4 ev = *(const float4*)&encw[(size_t)(n*WMAX + r)*E_ + (t<<2)];
      a.x += wv*ev.x; a.y += wv*ev.y; a.z += wv*ev.z; a.w += wv*ev.w;
    }
    *(float4*)&x0[n*832 + 256 + (t<<2)] = a;
    *(float4*)&ctxb[(n<<10) + (t<<2)] = a;
  }
}

// =================== LSTM combine: gates -> h (256 blocks) ===================
__global__ __launch_bounds__(256) void k_comb(const float* __restrict__ pL, int KS,
                                              const float* __restrict__ bih,
                                              const float* __restrict__ bhh,
                                              const float* __restrict__ cprev,
                                              float* __restrict__ dst){
  int bid = blockIdx.x, t = threadIdx.x;
  int b = bid >> 2; int u = ((bid & 3) << 8) + t;
  float g[4];
  #pragma unroll
  for (int gi=0; gi<4; ++gi){
    int col = (gi<<10) + u;
    float s = bih[col] + bhh[col];
    for (int p=0; p<KS; ++p) s += pL[(size_t)((p<<6)+b)*4096 + col];
    g[gi] = s;
  }
  float c = cprev[(b<<10)+u];
  float cn = sigmoidf_(g[1])*c + sigmoidf_(g[0])*tanhf(g[2]);
  dst[(b<<10)+u] = sigmoidf_(g[3])*tanhf(cn);
}

// =================== output combine ===================
__global__ __launch_bounds__(256) void k_comb_out(const float* __restrict__ pO,
                                                  const float* __restrict__ bout,
                                                  float* __restrict__ out){
  int idx = blockIdx.x*256 + threadIdx.x;
  int b = idx / 160; int c = idx - b*160;
  float s = bout[c];
  #pragma unroll
  for (int ks=0; ks<8; ++ks) s += pO[(size_t)((ks<<6)+b)*160 + c];
  out[idx] = s;
}

extern "C" void kernel_launch(void* const* d_in, const int* in_sizes, int n_in,
                              void* d_out, int out_size, void* d_ws, size_t ws_size,
                              hipStream_t stream){
  const float* enc   = (const float*)d_in[0];
  const float* indec = (const float*)d_in[1];
  const float* spkr  = (const float*)d_in[2];
  const float* prev  = (const float*)d_in[3];
  const float* hid   = (const float*)d_in[4];
  const float* cell  = (const float*)d_in[5];
  const int*   lens  = (const int*)d_in[6];
  const float* Wenc  = (const float*)d_in[7];
  const float* benc  = (const float*)d_in[8];
  const float* Wspkr = (const float*)d_in[9];
  const float* convw = (const float*)d_in[10];
  const float* Wdec  = (const float*)d_in[11];
  const float* Wproj = (const float*)d_in[12];
  /* d_in[13] = b_proj: uniform shift, cancels in normalized attention weights */
  const float* Wpre1 = (const float*)d_in[14];
  const float* bpre1 = (const float*)d_in[15];
  const float* Wpre2 = (const float*)d_in[16];
  const float* bpre2 = (const float*)d_in[17];
  const float* Wih0  = (const float*)d_in[18];
  const float* Whh0  = (const float*)d_in[19];
  const float* bih0  = (const float*)d_in[20];
  const float* bhh0  = (const float*)d_in[21];
  const float* Wih1  = (const float*)d_in[22];
  const float* Whh1  = (const float*)d_in[23];
  const float* bih1  = (const float*)d_in[24];
  const float* bhh1  = (const float*)d_in[25];
  const float* Wout  = (const float*)d_in[26];
  const float* bout  = (const float*)d_in[27];
  (void)in_sizes; (void)n_in; (void)out_size; (void)ws_size;

  float* ws = (float*)d_ws;
  size_t off = 0;
  auto alloc = [&](size_t nf){ float* p = ws + off; off += nf; return p; };
  const size_t SL = (size_t)64*4096;          // one partial slot
  float* pA     = alloc((size_t)8*64*256);
  float* p1x    = alloc((size_t)64*512);
  float* pP2    = alloc((size_t)4*64*256);
  float* x0     = alloc(64*832);
  float* ctxb   = alloc((size_t)64*1024);
  float* h1     = alloc((size_t)64*1024);
  float* h2b    = alloc((size_t)64*1024);
  float* pO     = alloc((size_t)8*64*160);
  float* paw    = alloc(64*49 + 15);
  int*   lo_w   = (int*)alloc(64);
  int*   wl_w   = (int*)alloc(64);
  float* encw   = alloc((size_t)64*WMAX*512);
  float* pE     = alloc((size_t)4*1216*256);
  float* pL0    = alloc(8*SL);                // slots 0-3: Whh0 part, 4-7: Wih0 part
  float* pL1    = alloc(8*SL);                // slots 0-3: Whh1 part, 4-7: Wih1 part
  float* out    = (float*)d_out;

  // K1: argmax+gather (0-63) | Wdec GEMM (64-95) | pre1 GEMM (96-103)
  k_front3<<<104,256,0,stream>>>(prev, lens, enc, indec, spkr,
                                 Wpre1, bpre1, hid, Wdec,
                                 lo_w, wl_w, encw, paw, x0, pA, p1x);
  // K2: enc GEMM (0-303) | pre2 (304-319) | Whh0*h0 (320-575) | Whh1*h1prev (576-831)
  k_mega<<<832,256,0,stream>>>(encw, Wenc, pE, p1x, Wpre2, pP2,
                               hid, Whh0, Whh1, pL0, pL1);
  // K3: attention (0-63) | pre2 combine (64-79)
  k_att2<<<80,256,0,stream>>>(pE, pA, benc, convw, Wproj, spkr, Wspkr,
                              paw, wl_w, encw, pP2, bpre2, x0, ctxb);
  // K4: LSTM0 I-part (Wih0 * x0), K=832
  k_lstmI<<<256,256,0,stream>>>(x0, 832, Wih0, pL0 + 4*SL, 4, 832);
  // K5: combine layer 0 -> h1
  k_comb<<<256,256,0,stream>>>(pL0, 8, bih0, bhh0, cell, h1);
  // K6: LSTM1 I-part (Wih1 * h1), K=1024
  k_lstmI<<<256,256,0,stream>>>(h1, 1024, Wih1, pL1 + 4*SL, 4, 1024);
  // K7: combine layer 1 -> h2
  k_comb<<<256,256,0,stream>>>(pL1, 8, bih1, bhh1, cell + 64*1024, h2b);
  // K8: out GEMM (tiled, Wout read once) -> partials
  k_gemmA<<<1*3*8,256,0,stream>>>(h2b, 1024, ctxb, 1024, Wout,
                                  pO, 1536, 160, 1, 3, 8);
  // K9: output combine
  k_comb_out<<<40,256,0,stream>>>(pO, bout, out);
}

// Round 5
// 141.801 us; speedup vs baseline: 1.0773x; 1.0773x over previous
//
#include <hip/hip_runtime.h>
#include <math.h>

#define N_    64
#define T_    1024
#define E_    512
#define A_    256
#define S_    64
#define O_    80
#define HID_  1024
#define WMAX  19
#define SLOT  ((size_t)64*4096)

typedef __attribute__((ext_vector_type(8))) short bh8;
typedef __attribute__((ext_vector_type(4))) float fx4;

__device__ __forceinline__ float sigmoidf_(float x){ return 1.f/(1.f+expf(-x)); }
__device__ __forceinline__ unsigned pk2_(float a, float b){
  unsigned ua = __float_as_uint(a), ub = __float_as_uint(b);
  ua = (ua + 0x7fffu + ((ua>>16)&1u)) >> 16;
  ub = (ub + 0x7fffu + ((ub>>16)&1u)) >> 16;
  return ua | (ub<<16);
}

// =================== generic tiled GEMM body ===================
struct GemmS { float x_s[2][64][68]; float w_s[2][64][68]; };

__device__ void gemm_body(const float* __restrict__ X, int xStride,
                          const float* __restrict__ X2, int Ksplit,
                          const float* __restrict__ W,
                          float* __restrict__ partial,
                          int K, int C, int nMt, int nCt, int KS,
                          int bid, int t, GemmS& sm){
  int mt = bid % nMt; int rest = bid / nMt;
  int ct = rest % nCt; int ks = rest / nCt;
  int m0 = mt << 6; int c0 = ct << 6;
  int M = nMt << 6;
  int nch = (K + 63) >> 6;
  int ch0 = (ks*nch)/KS, ch1 = ((ks+1)*nch)/KS;
  int bi = t >> 4, j = t & 15;
  float4 px[4], pw[4];

  auto ld = [&](int ch){
    int k0 = ch << 6;
    #pragma unroll
    for (int i=0;i<4;i++){
      int lin = i*256+t; int bl = lin>>4, kq = lin&15;
      int k = k0 + (kq<<2);
      float4 v = make_float4(0.f,0.f,0.f,0.f);
      if (k < K){
        if (X2 != nullptr && k >= Ksplit){
          v = *(const float4*)&X2[(size_t)bl*1024 + (k - Ksplit)];
        } else {
          v = *(const float4*)&X[(size_t)(m0+bl)*xStride + k];
        }
      }
      px[i] = v;
    }
    #pragma unroll
    for (int i=0;i<4;i++){
      int lin = i*256+t; int kk = lin>>4, cq = lin&15;
      int k = k0 + kk, c = c0 + (cq<<2);
      float4 v = make_float4(0.f,0.f,0.f,0.f);
      if (k < K && c < C) v = *(const float4*)&W[(size_t)k*C + c];
      pw[i] = v;
    }
  };
  auto st = [&](int buf){
    #pragma unroll
    for (int i=0;i<4;i++){
      int lin = i*256+t; int bl = lin>>4, kq = lin&15;
      *(float4*)&sm.x_s[buf][bl][kq<<2] = px[i];
    }
    #pragma unroll
    for (int i=0;i<4;i++){
      int lin = i*256+t; int kk = lin>>4, cq = lin&15;
      *(float4*)&sm.w_s[buf][kk][cq<<2] = pw[i];
    }
  };

  float4 acc[4];
  #pragma unroll
  for (int m=0;m<4;m++) acc[m] = make_float4(0.f,0.f,0.f,0.f);

  ld(ch0); st(0); __syncthreads();
  int buf = 0;
  for (int ch = ch0; ch < ch1; ++ch){
    if (ch+1 < ch1) ld(ch+1);
    #pragma unroll
    for (int kq=0;kq<16;kq++){
      float4 xv[4], wv[4];
      #pragma unroll
      for (int bb=0;bb<4;bb++) xv[bb] = *(const float4*)&sm.x_s[buf][(bi<<2)+bb][kq<<2];
      #pragma unroll
      for (int kk=0;kk<4;kk++) wv[kk] = *(const float4*)&sm.w_s[buf][(kq<<2)+kk][j<<2];
      #pragma unroll
      for (int bb=0;bb<4;bb++){
        float s0=xv[bb].x, s1=xv[bb].y, s2=xv[bb].z, s3=xv[bb].w;
        acc[bb].x += s0*wv[0].x + s1*wv[1].x + s2*wv[2].x + s3*wv[3].x;
        acc[bb].y += s0*wv[0].y + s1*wv[1].y + s2*wv[2].y + s3*wv[3].y;
        acc[bb].z += s0*wv[0].z + s1*wv[1].z + s2*wv[2].z + s3*wv[3].z;
        acc[bb].w += s0*wv[0].w + s1*wv[1].w + s2*wv[2].w + s3*wv[3].w;
      }
    }
    if (ch+1 < ch1){ st(buf^1); __syncthreads(); }
    buf ^= 1;
  }
  int c = c0 + (j<<2);
  if (c < C){
    #pragma unroll
    for (int bb=0;bb<4;bb++){
      int bl = (bi<<2)+bb;
      *(float4*)&partial[(size_t)(ks*M + m0 + bl)*C + c] = acc[bb];
    }
  }
}

__global__ __launch_bounds__(256) void k_gemmA(const float* __restrict__ X, int xStride,
                                               const float* __restrict__ X2, int Ksplit,
                                               const float* __restrict__ W,
                                               float* __restrict__ partial,
                                               int K, int C, int nMt, int nCt, int KS){
  __shared__ GemmS sm;
  gemm_body(X,xStride,X2,Ksplit,W,partial,K,C,nMt,nCt,KS,blockIdx.x,threadIdx.x,sm);
}

// =================== LSTM gates GEMM body (bf16 MFMA) ===================
struct LstmS { uint4 WlA[2][512]; uint4 XlA[2][512]; float outb[64][68]; };

__device__ void lstm_body(const float* __restrict__ xA, int KxA,
                          const float* __restrict__ xB,
                          const float* __restrict__ Wih,
                          const float* __restrict__ Whh,
                          float* __restrict__ partial, int KS, int Klen,
                          int bid, int t, LstmS& sm){
  int Mblk = bid & 63;
  int ks = bid >> 6;
  int r0 = Mblk << 6;
  int nch = Klen >> 6;
  int ch0 = (ks*nch)/KS, ch1 = ((ks+1)*nch)/KS;
  int wid = t >> 6, lane = t & 63;

  float4 rw[2][2], rx[2][2];
  auto ld = [&](int ch){
    int k0 = ch << 6;
    #pragma unroll
    for (int u=0;u<2;u++){
      int g = t + (u<<8); int row = g>>3; int k = k0 + ((g&7)<<3);
      const float* sw;
      const float* sx;
      if (k < KxA){ sw = &Wih[(size_t)(r0+row)*KxA + k]; sx = &xA[(size_t)row*KxA + k]; }
      else        { sw = &Whh[((size_t)(r0+row)<<10) + (k - KxA)]; sx = &xB[((size_t)row<<10) + (k - KxA)]; }
      rw[u][0] = *(const float4*)sw; rw[u][1] = *(const float4*)(sw+4);
      rx[u][0] = *(const float4*)sx; rx[u][1] = *(const float4*)(sx+4);
    }
  };
  auto cvst = [&](int buf){
    #pragma unroll
    for (int u=0;u<2;u++){
      int g = t + (u<<8); int row = g>>3, gk = g&7;
      int byte = row*128 + ((gk ^ (row&7))<<4);
      uint4 vw, vx;
      vw.x = pk2_(rw[u][0].x, rw[u][0].y); vw.y = pk2_(rw[u][0].z, rw[u][0].w);
      vw.z = pk2_(rw[u][1].x, rw[u][1].y); vw.w = pk2_(rw[u][1].z, rw[u][1].w);
      vx.x = pk2_(rx[u][0].x, rx[u][0].y); vx.y = pk2_(rx[u][0].z, rx[u][0].w);
      vx.z = pk2_(rx[u][1].x, rx[u][1].y); vx.w = pk2_(rx[u][1].z, rx[u][1].w);
      *(uint4*)((char*)&sm.WlA[buf][0] + byte) = vw;
      *(uint4*)((char*)&sm.XlA[buf][0] + byte) = vx;
    }
  };

  fx4 acc[4];
  #pragma unroll
  for (int nt=0;nt<4;nt++) acc[nt] = (fx4){0.f,0.f,0.f,0.f};

  ld(ch0); cvst(0); __syncthreads();
  int buf = 0;
  for (int ch = ch0; ch < ch1; ++ch){
    if (ch+1 < ch1) ld(ch+1);
    int rowA = (wid<<4) + (lane&15);
    #pragma unroll
    for (int s=0;s<2;s++){
      int gA = (s<<2) + (lane>>4);
      bh8 a = *(bh8*)((char*)&sm.WlA[buf][0] + rowA*128 + ((gA ^ (rowA&7))<<4));
      #pragma unroll
      for (int nt=0;nt<4;nt++){
        int rowB = (nt<<4) + (lane&15);
        bh8 bf = *(bh8*)((char*)&sm.XlA[buf][0] + rowB*128 + ((gA ^ (rowB&7))<<4));
        acc[nt] = __builtin_amdgcn_mfma_f32_16x16x32_bf16(a, bf, acc[nt], 0, 0, 0);
      }
    }
    if (ch+1 < ch1){ cvst(buf^1); __syncthreads(); }
    buf ^= 1;
  }
  __syncthreads();
  #pragma unroll
  for (int nt=0;nt<4;nt++){
    #pragma unroll
    for (int q=0;q<4;q++)
      sm.outb[(nt<<4)+(lane&15)][(wid<<4)+((lane>>4)<<2)+q] = acc[nt][q];
  }
  __syncthreads();
  #pragma unroll
  for (int i=0;i<4;i++){
    int idx = i*256+t; int b = idx>>4; int r4 = (idx&15)<<2;
    float4 o = *(const float4*)&sm.outb[b][r4];
    *(float4*)&partial[(size_t)((ks<<6)+b)*4096 + r0 + r4] = o;
  }
}

// I-part standalone kernel (Wih * x only)
__global__ __launch_bounds__(256) void k_lstmI(const float* __restrict__ xA, int KxA,
                                               const float* __restrict__ Wih,
                                               float* __restrict__ partial,
                                               int KS, int Klen){
  __shared__ LstmS sm;
  lstm_body(xA, KxA, nullptr, Wih, nullptr, partial, KS, Klen,
            blockIdx.x, threadIdx.x, sm);
}

// =================== K1: argmax+gather | Wdec GEMM | pre1 GEMM | Whh1 rider ===================
__global__ __launch_bounds__(256) void k_front3(
    const float* __restrict__ prev, const int* __restrict__ lens,
    const float* __restrict__ enc, const float* __restrict__ indec,
    const float* __restrict__ spkr,
    const float* __restrict__ W1, const float* __restrict__ b1,
    const float* __restrict__ hid, const float* __restrict__ Wdec,
    const float* __restrict__ Whh1,
    int* __restrict__ lo_out, int* __restrict__ wl_out,
    float* __restrict__ encw, float* __restrict__ paw,
    float* __restrict__ x0, float* __restrict__ pA,
    float* __restrict__ p1x, float* __restrict__ pL1){
  __shared__ __align__(16) char smem_raw[sizeof(GemmS)];
  int bid = blockIdx.x, t = threadIdx.x;

  if (bid < 64){
    int n = bid;
    float* sv = (float*)smem_raw;
    int*   si = (int*)(smem_raw + 1024);
    int*   meta = (int*)(smem_raw + 2048);
    const float* p = prev + n*T_;
    float bv = -1e30f; int bi2 = 0x7fffffff;
    #pragma unroll
    for (int i=0;i<4;i++){
      int idx = t + (i<<8);
      float v = p[idx];
      if (v > bv || (v == bv && idx < bi2)){ bv = v; bi2 = idx; }
    }
    sv[t]=bv; si[t]=bi2; __syncthreads();
    for (int s=128; s>0; s>>=1){
      if (t < s){
        float v2 = sv[t+s]; int i2 = si[t+s];
        if (v2 > sv[t] || (v2 == sv[t] && i2 < si[t])){ sv[t]=v2; si[t]=i2; }
      }
      __syncthreads();
    }
    if (t==0){
      int len = lens[n]; len = len < 1 ? 1 : (len > T_ ? T_ : len);
      int idx = si[0];
      int lo = idx - 9; lo = lo < 0 ? 0 : lo; if (lo > len-1) lo = len-1;
      int hi = idx + 9; hi = hi < 0 ? 0 : hi; if (hi > len-1) hi = len-1;
      meta[0] = lo; meta[1] = hi - lo + 1;
      lo_out[n] = lo; wl_out[n] = hi - lo + 1;
    }
    __syncthreads();
    int lo = meta[0], wl = meta[1];
    #pragma unroll
    for (int i=0;i<10;i++){
      int lin = i*256 + t;
      int r = lin >> 7, e4 = (lin & 127) << 2;
      if (r < WMAX){
        float4 v = make_float4(0.f,0.f,0.f,0.f);
        if (r < wl) v = *(const float4*)&enc[(size_t)((n<<10)+lo+r)*E_ + e4];
        *(float4*)&encw[(size_t)(n*WMAX + r)*E_ + e4] = v;
      }
    }
    if (t < 49){
      int tt = lo - 15 + t;
      paw[n*49 + t] = (tt >= 0 && tt < T_) ? prev[(n<<10)+tt] : 0.f;
    }
    if (t < 16)
      *(float4*)&x0[n*832 + 768 + (t<<2)] = *(const float4*)&spkr[(n<<6) + (t<<2)];

  } else if (bid < 96){
    gemm_body(hid, 1024, hid + 64*1024, 1024, Wdec,
              pA, 2048, 256, 1, 4, 8, bid - 64, t, *(GemmS*)smem_raw);

  } else if (bid < 104){
    // pre1 GEMM (8 blocks)
    int d = bid - 96;
    float* xs = (float*)smem_raw;
    #pragma unroll
    for (int i=0;i<9;i++){
      int q = i*256 + t;
      if (q < 2304){
        int b = q/36; int k4 = (q - b*36) << 2;
        float4 v;
        if (k4 < O_) v = *(const float4*)&indec[b*O_ + k4];
        else         v = *(const float4*)&spkr[(b<<6) + (k4-O_)];
        *(float4*)&xs[b*144 + k4] = v;
      }
    }
    __syncthreads();
    int bi = t >> 4, j = t & 15;
    int c0 = (d<<6) + (j<<2);
    float4 acc[4];
    #pragma unroll
    for (int rr=0;rr<4;rr++) acc[rr] = make_float4(0.f,0.f,0.f,0.f);
    #pragma unroll 4
    for (int k=0;k<144;k++){
      float4 wv = *(const float4*)&W1[(size_t)k*512 + c0];
      #pragma unroll
      for (int rr=0;rr<4;rr++){
        float xv = xs[((bi<<2)+rr)*144 + k];
        acc[rr].x += xv*wv.x; acc[rr].y += xv*wv.y; acc[rr].z += xv*wv.z; acc[rr].w += xv*wv.w;
      }
    }
    float4 bv = *(const float4*)&b1[c0];
    #pragma unroll
    for (int rr=0;rr<4;rr++){
      float4 o;
      o.x = fmaxf(acc[rr].x + bv.x, 0.f);
      o.y = fmaxf(acc[rr].y + bv.y, 0.f);
      o.z = fmaxf(acc[rr].z + bv.z, 0.f);
      o.w = fmaxf(acc[rr].w + bv.w, 0.f);
      *(float4*)&p1x[(size_t)((bi<<2)+rr)*512 + c0] = o;
    }

  } else {
    // Whh1 * hid1 rider (128 blocks, KS=2 -> pL1 slots 0-1)
    lstm_body(nullptr, 0, hid + 64*1024, nullptr, Whh1,
              pL1, 2, 1024, bid - 104, t, *(LstmS*)smem_raw);
  }
}

// =================== K2: enc GEMM | pre2 GEMM | Whh0 rider ===================
__global__ __launch_bounds__(256) void k_gemmB(const float* __restrict__ encw,
                                               const float* __restrict__ Wenc,
                                               float* __restrict__ pE,
                                               const float* __restrict__ p1x,
                                               const float* __restrict__ W2,
                                               float* __restrict__ pP2,
                                               const float* __restrict__ hid,
                                               const float* __restrict__ Whh0,
                                               float* __restrict__ pL0){
  __shared__ __align__(16) char smem_raw[sizeof(GemmS)];
  int bid = blockIdx.x, t = threadIdx.x;
  if (bid < 304)
    gemm_body(encw, 512, nullptr, 0, Wenc, pE, 512, 256, 19, 4, 4,
              bid, t, *(GemmS*)smem_raw);
  else if (bid < 320)
    gemm_body(p1x, 512, nullptr, 0, W2, pP2, 512, 256, 1, 4, 4,
              bid - 304, t, *(GemmS*)smem_raw);
  else
    lstm_body(nullptr, 0, hid, nullptr, Whh0,
              pL0, 2, 1024, bid - 320, t, *(LstmS*)smem_raw);
}

// =================== K3: attention epilogue+softmax+ctx | pre2 combine ===================
__global__ __launch_bounds__(256) void k_att2(const float* __restrict__ pE,
    const float* __restrict__ pA, const float* __restrict__ benc,
    const float* __restrict__ convw, const float* __restrict__ Wproj,
    const float* __restrict__ spkr, const float* __restrict__ Wspkr,
    const float* __restrict__ paw, const int* __restrict__ wl_w,
    const float* __restrict__ encw,
    const float* __restrict__ pP2, const float* __restrict__ b2,
    float* __restrict__ x0, float* __restrict__ ctxb){
  __shared__ float cw_s[256*31];
  __shared__ float cv_s[WMAX*256];
  __shared__ float attb_s[256];
  __shared__ float pa_s[49];
  __shared__ float wlog_s[WMAX];
  __shared__ float w_s[WMAX];
  int t = threadIdx.x;

  if (blockIdx.x >= 64){
    int idx = (blockIdx.x - 64)*256 + t;
    int b = idx >> 6; int c4 = (idx & 63) << 2;
    float4 v = *(const float4*)&b2[c4];
    #pragma unroll
    for (int p=0;p<4;p++){
      float4 u = *(const float4*)&pP2[(size_t)((p<<6)+b)*A_ + c4];
      v.x+=u.x; v.y+=u.y; v.z+=u.z; v.w+=u.w;
    }
    v.x=fmaxf(v.x,0.f); v.y=fmaxf(v.y,0.f); v.z=fmaxf(v.z,0.f); v.w=fmaxf(v.w,0.f);
    *(float4*)&x0[b*832 + c4] = v;
    return;
  }

  int n = blockIdx.x;
  int wl = wl_w[n];
  for (int lin = t; lin < 256*31; lin += 256) cw_s[lin] = convw[lin];
  if (t < 49) pa_s[t] = paw[n*49 + t];
  {
    float v = 0.f;
    #pragma unroll
    for (int p=0;p<8;p++) v += pA[(size_t)((p<<6)+n)*A_ + t];
    float sd = 0.f;
    #pragma unroll 16
    for (int s=0;s<S_;s++) sd += spkr[(n<<6)+s]*Wspkr[(s<<8)+t];
    attb_s[t] = v + sd/(1.f+fabsf(sd));
  }
  __syncthreads();
  for (int r=0; r<wl; ++r){
    float cv = 0.f;
    #pragma unroll
    for (int k=0;k<31;k++) cv += cw_s[t*31+k]*pa_s[r+k];
    cv_s[(r<<8)+t] = cv;
  }
  __syncthreads();
  int wid = t>>6, lane = t&63, a0 = lane<<2;
  float4 be4 = *(const float4*)&benc[a0];
  float4 wp4 = *(const float4*)&Wproj[a0];
  float4 ab4 = *(const float4*)&attb_s[a0];
  for (int r = wid; r < wl; r += 4){
    float4 sv = make_float4(0.f,0.f,0.f,0.f);
    #pragma unroll
    for (int ks=0;ks<4;ks++){
      const float4 u = *(const float4*)&pE[(size_t)(ks*1216 + n*WMAX + r)*A_ + a0];
      sv.x+=u.x; sv.y+=u.y; sv.z+=u.z; sv.w+=u.w;
    }
    sv.x += be4.x; sv.y += be4.y; sv.z += be4.z; sv.w += be4.w;
    const float4 cv4 = *(const float4*)&cv_s[(r<<8)+a0];
    float e0 = sv.x/(1.f+fabsf(sv.x)) + ab4.x + cv4.x;
    float e1 = sv.y/(1.f+fabsf(sv.y)) + ab4.y + cv4.y;
    float e2 = sv.z/(1.f+fabsf(sv.z)) + ab4.z + cv4.z;
    float e3 = sv.w/(1.f+fabsf(sv.w)) + ab4.w + cv4.w;
    float vv = tanhf(e0)*wp4.x + tanhf(e1)*wp4.y + tanhf(e2)*wp4.z + tanhf(e3)*wp4.w;
    #pragma unroll
    for (int off=32; off; off >>= 1) vv += __shfl_xor(vv, off, 64);
    if (lane == 0) wlog_s[r] = vv;
  }
  __syncthreads();
  if (t < 32){
    float l = (t < wl) ? wlog_s[t] : -1e30f;
    float mx = l;
    #pragma unroll
    for (int off=16; off; off >>= 1) mx = fmaxf(mx, __shfl_xor(mx, off, 32));
    float ex = (t < wl) ? expf(l - mx) : 0.f;
    float sm = ex;
    #pragma unroll
    for (int off=16; off; off >>= 1) sm += __shfl_xor(sm, off, 32);
    if (t < wl) w_s[t] = ex / sm;
  }
  __syncthreads();
  if (t < 128){
    float4 a = make_float4(0.f,0.f,0.f,0.f);
    for (int r=0; r<wl; ++r){
      float wv = w_s[r];
      const float4 ev = *(const float4*)&encw[(size_t)(n*WMAX + r)*E_ + (t<<2)];
      a.x += wv*ev.x; a.y += wv*ev.y; a.z += wv*ev.z; a.w += wv*ev.w;
    }
    *(float4*)&x0[n*832 + 256 + (t<<2)] = a;
    *(float4*)&ctxb[(n<<10) + (t<<2)] = a;
  }
}

// =================== LSTM combine: gates -> h (256 blocks) ===================
__global__ __launch_bounds__(256) void k_comb(const float* __restrict__ pL, int NS,
                                              const float* __restrict__ bih,
                                              const float* __restrict__ bhh,
                                              const float* __restrict__ cprev,
                                              float* __restrict__ dst){
  int bid = blockIdx.x, t = threadIdx.x;
  int b = bid >> 2; int u = ((bid & 3) << 8) + t;
  float g[4];
  #pragma unroll
  for (int gi=0; gi<4; ++gi){
    int col = (gi<<10) + u;
    float s = bih[col] + bhh[col];
    for (int q=0; q<NS; ++q) s += pL[(size_t)((q<<6)+b)*4096 + col];
    g[gi] = s;
  }
  float c = cprev[(b<<10)+u];
  float cn = sigmoidf_(g[1])*c + sigmoidf_(g[0])*tanhf(g[2]);
  dst[(b<<10)+u] = sigmoidf_(g[3])*tanhf(cn);
}

// =================== output combine ===================
__global__ __launch_bounds__(256) void k_comb_out(const float* __restrict__ pO,
                                                  const float* __restrict__ bout,
                                                  float* __restrict__ out){
  int idx = blockIdx.x*256 + threadIdx.x;
  int b = idx / 160; int c = idx - b*160;
  float s = bout[c];
  #pragma unroll
  for (int ks=0; ks<8; ++ks) s += pO[(size_t)((ks<<6)+b)*160 + c];
  out[idx] = s;
}

extern "C" void kernel_launch(void* const* d_in, const int* in_sizes, int n_in,
                              void* d_out, int out_size, void* d_ws, size_t ws_size,
                              hipStream_t stream){
  const float* enc   = (const float*)d_in[0];
  const float* indec = (const float*)d_in[1];
  const float* spkr  = (const float*)d_in[2];
  const float* prev  = (const float*)d_in[3];
  const float* hid   = (const float*)d_in[4];
  const float* cell  = (const float*)d_in[5];
  const int*   lens  = (const int*)d_in[6];
  const float* Wenc  = (const float*)d_in[7];
  const float* benc  = (const float*)d_in[8];
  const float* Wspkr = (const float*)d_in[9];
  const float* convw = (const float*)d_in[10];
  const float* Wdec  = (const float*)d_in[11];
  const float* Wproj = (const float*)d_in[12];
  /* d_in[13] = b_proj: uniform shift, cancels in normalized attention weights */
  const float* Wpre1 = (const float*)d_in[14];
  const float* bpre1 = (const float*)d_in[15];
  const float* Wpre2 = (const float*)d_in[16];
  const float* bpre2 = (const float*)d_in[17];
  const float* Wih0  = (const float*)d_in[18];
  const float* Whh0  = (const float*)d_in[19];
  const float* bih0  = (const float*)d_in[20];
  const float* bhh0  = (const float*)d_in[21];
  const float* Wih1  = (const float*)d_in[22];
  const float* Whh1  = (const float*)d_in[23];
  const float* bih1  = (const float*)d_in[24];
  const float* bhh1  = (const float*)d_in[25];
  const float* Wout  = (const float*)d_in[26];
  const float* bout  = (const float*)d_in[27];
  (void)in_sizes; (void)n_in; (void)out_size; (void)ws_size;

  float* ws = (float*)d_ws;
  size_t off = 0;
  auto alloc = [&](size_t nf){ float* p = ws + off; off += nf; return p; };
  float* pA     = alloc((size_t)8*64*256);
  float* p1x    = alloc((size_t)64*512);
  float* pP2    = alloc((size_t)4*64*256);
  float* x0     = alloc(64*832);
  float* ctxb   = alloc((size_t)64*1024);
  float* h1     = alloc((size_t)64*1024);
  float* h2b    = alloc((size_t)64*1024);
  float* pO     = alloc((size_t)8*64*160);
  float* paw    = alloc(64*49 + 15);
  int*   lo_w   = (int*)alloc(64);
  int*   wl_w   = (int*)alloc(64);
  float* encw   = alloc((size_t)64*WMAX*512);
  float* pE     = alloc((size_t)4*1216*256);
  float* pL0    = alloc(6*SLOT);   // slots 0-1: Whh0 (KS=2), slots 2-5: Wih0 (KS=4)
  float* pL1    = alloc(6*SLOT);   // slots 0-1: Whh1 (KS=2), slots 2-5: Wih1 (KS=4)
  float* out    = (float*)d_out;

  // K1: front (0-63) | Wdec (64-95) | pre1 (96-103) | Whh1*hid1 (104-231)
  k_front3<<<232,256,0,stream>>>(prev, lens, enc, indec, spkr,
                                 Wpre1, bpre1, hid, Wdec, Whh1,
                                 lo_w, wl_w, encw, paw, x0, pA, p1x, pL1);
  // K2: enc GEMM (0-303) | pre2 (304-319) | Whh0*hid0 (320-447)
  k_gemmB<<<448,256,0,stream>>>(encw, Wenc, pE, p1x, Wpre2, pP2,
                                hid, Whh0, pL0);
  // K3: attention (0-63) | pre2 combine (64-79)
  k_att2<<<80,256,0,stream>>>(pE, pA, benc, convw, Wproj, spkr, Wspkr,
                              paw, wl_w, encw, pP2, bpre2, x0, ctxb);
  // K4: Wih0 * x0 (K=832) -> pL0 slots 2-5
  k_lstmI<<<256,256,0,stream>>>(x0, 832, Wih0, pL0 + 2*SLOT, 4, 832);
  // K5: combine layer 0 -> h1 (6 slots)
  k_comb<<<256,256,0,stream>>>(pL0, 6, bih0, bhh0, cell, h1);
  // K6: Wih1 * h1 (K=1024) -> pL1 slots 2-5
  k_lstmI<<<256,256,0,stream>>>(h1, 1024, Wih1, pL1 + 2*SLOT, 4, 1024);
  // K7: combine layer 1 -> h2b (6 slots)
  k_comb<<<256,256,0,stream>>>(pL1, 6, bih1, bhh1, cell + 64*1024, h2b);
  // K8: out GEMM (tiled, Wout read once) -> partials
  k_gemmA<<<1*3*8,256,0,stream>>>(h2b, 1024, ctxb, 1024, Wout,
                                  pO, 1536, 160, 1, 3, 8);
  // K9: output combine
  k_comb_out<<<40,256,0,stream>>>(pO, bout, out);
}